// Round 1
// baseline (421.137 us; speedup 1.0000x reference)
//
#include <hip/hip_runtime.h>
#include <hip/hip_bf16.h>

#define BATCH 4096
#define NTHR 512

typedef __attribute__((ext_vector_type(8))) short bf16x8;
typedef __attribute__((ext_vector_type(4))) float f32x4;
typedef __attribute__((ext_vector_type(4))) short short4v;

// CK-style barrier: drain LDS only, leave global prefetches in flight
#define BAR() asm volatile("s_waitcnt lgkmcnt(0)\n\ts_barrier" ::: "memory")
#define MFMA16(a, b, c) __builtin_amdgcn_mfma_f32_16x16x32_bf16(a, b, c, 0, 0, 0)

// dh-sorted packing: group g (= degree) has cnt(g) units, prefix off1(g)
__host__ __device__ __forceinline__ int off1(int g) { return (g <= 16) ? 17 * g : 16 * g + 16; }
__host__ __device__ __forceinline__ int cntg(int g) { return (g < 16) ? 17 : 16; }
__host__ __device__ __forceinline__ int unitOf(int p) {
    int gp, jp;
    if (p < 272) { gp = p / 17; jp = p - gp * 17; }
    else         { gp = (p >> 4) - 1; jp = p & 15; }
    return gp + 63 * jp;
}
__device__ __forceinline__ short f2bf(float f) {
    __hip_bfloat16 h = __float2bfloat16(f);
    return *reinterpret_cast<short*>(&h);
}
__device__ __forceinline__ float bfrnd(float f) {
    __hip_bfloat16 h = __float2bfloat16(f);
    return __bfloat162float(h);
}

// ---------------- prep6: LDS-staged coalesced packing (512 thr) — unchanged ----------------
__global__ void prep6(const float* __restrict__ W0, const float* __restrict__ b0,
                      const float* __restrict__ W1, const float* __restrict__ b1,
                      const float* __restrict__ W2,
                      short* __restrict__ W1f, short* __restrict__ W2f,
                      short* __restrict__ W0f, float* __restrict__ b1p) {
    __shared__ short ws[16][1024];
    const int b = blockIdx.x, t = threadIdx.x;
    if (b < 72) {
        const bool isW1 = (b < 64);
        const int n = t >> 5;                 // staged slot 0..15
        int u;
        if (isW1) u = unitOf(b * 16 + n);
        else { const int c = b - 64; u = (n & 1) ? (64 + c * 8 + (n >> 1)) : (c * 8 + (n >> 1)); }
        const float* src = isW1 ? (W1 + (long)u * 1024) : (W2 + (long)u * 1024);
        const int c0 = (t & 31) * 4;
#pragma unroll
        for (int j = 0; j < 8; ++j) {
            int c = c0 + j * 128;
            float4 v = *(const float4*)&src[c];
            short4v sv;
            sv[0] = f2bf(v.x); sv[1] = f2bf(v.y); sv[2] = f2bf(v.z); sv[3] = f2bf(v.w);
            *(short4v*)&ws[n][c] = sv;
        }
        __syncthreads();
#pragma unroll 1
        for (int it = 0; it < 8; ++it) {
            int v = t + it * 512;
            if (v < 4032) {
                int g = v >> 6, lane2 = v & 63;
                int nn = lane2 & 15, aq2 = lane2 >> 4;
                bf16x8 pk;
#pragma unroll
                for (int e = 0; e < 8; ++e) {
                    int k = aq2 * 8 + e;
                    pk[e] = (k < cntg(g)) ? ws[nn][g + 63 * k] : (short)0;
                }
                if (isW1) *(bf16x8*)&W1f[(((long)g * 64 + b) * 64 + lane2) * 8] = pk;
                else      *(bf16x8*)&W2f[(((long)g * 8 + (b - 64)) * 64 + lane2) * 8] = pk;
            }
        }
    } else if (b < 88) {
        const int bb = b - 72;
#pragma unroll 1
        for (int j = 0; j < 16; ++j) {
            int q = t + j * 512;
            if (q < 8064) {
                int idx = bb * 8064 + q;
                int g = idx >> 11, rem = idx & 2047;
                int n2 = rem >> 10, kt = (rem >> 9) & 1, lane2 = (rem >> 3) & 63, e = rem & 7;
                int sl = n2 * 16 + (lane2 & 15);
                int kp = kt * 32 + ((lane2 >> 4) << 3) + e;
                float val = 0.f;
                if (sl < cntg(g)) {
                    int u = unitOf(off1(g) + sl);
                    if (kp == 0) val = b0[u];
                    else if (kp - 1 <= g) val = W0[u * 64 + kp - 1];
                }
                W0f[idx] = f2bf(val);
            }
        }
    } else {
        for (int p = t; p < 1024; p += 512) b1p[p] = b1[unitOf(p)];
    }
}

// ---------------- made7: window scheme ----------------
// Wave w exclusively runs steps i = 8w..8w+7 (the whole x->h1->h2->z chain same-wave,
// no barriers). It owns private acc2 copies of the h2-accumulator tiles covering its
// groups (8w-1..8w+6). h1[g]/h2[g] are published into double-buffered LDS rings
// (parity = (g>>3)&1, slot = g&7); at each window boundary (ONE barrier) the remaining
// waves batch-apply the previous window's 8 groups into their acc2/zacc.
// h1[i] = relu(partialMFMA(xhist cols 0..i) + x_i * W0col) — rank-1 update removes the
// xhist->MFMA round trip for the fresh column from the critical path.
__global__ __launch_bounds__(NTHR, 2) void made7(
    const float* __restrict__ uin, const float* __restrict__ b2,
    const float* __restrict__ W0,
    const short* __restrict__ W1f, const short* __restrict__ W2f,
    const short* __restrict__ W0f, const float* __restrict__ b1p,
    float* __restrict__ out) {

    __shared__ __align__(16) short h1w[2][8][16][40];   // [par][slot][m][j], cols 17..31 stay 0
    __shared__ __align__(16) short h2w[2][8][16][40];
    __shared__ __align__(16) short xhist[16][80];       // [m][k']: k'=0 bias 1.0, k'=i+1 -> x_i
    __shared__ __align__(16) float uT[64][16];
    __shared__ __align__(16) float xLs[16][68];
    __shared__ float ldjpart[8][16];

    const int t = threadIdx.x, lane = t & 63, wv = t >> 6;
    const int n = lane & 15, aq = lane >> 4;
    const int rowbase = blockIdx.x * 16;

    {   // zero LDS (K pads must stay 0 forever)
        int* z1 = (int*)&h1w[0][0][0][0];
#pragma unroll 1
        for (int idx = t; idx < 5120; idx += NTHR) z1[idx] = 0;
        int* z2 = (int*)&h2w[0][0][0][0];
#pragma unroll 1
        for (int idx = t; idx < 5120; idx += NTHR) z2[idx] = 0;
        int* z3 = (int*)&xhist[0][0];
#pragma unroll 1
        for (int idx = t; idx < 640; idx += NTHR) z3[idx] = 0;
    }
    if (t < 256) {
        int r = t >> 4, c0 = (t & 15) * 4;
        float4 v = *(const float4*)&uin[(long)(rowbase + r) * 64 + c0];
        uT[c0 + 0][r] = v.x; uT[c0 + 1][r] = v.y; uT[c0 + 2][r] = v.z; uT[c0 + 3][r] = v.w;
    }

    // private tile range: tiles covering groups [gA, gB]
    const int gA = (wv == 0) ? 0 : 8 * wv - 1;
    const int gB = (8 * wv + 6 > 62) ? 62 : 8 * wv + 6;
    const int TLO = off1(gA) >> 4;
    const int NT = ((off1(gB) + cntg(gB) - 1) >> 4) - TLO + 1;   // 8 or 9

    f32x4 acc2own[9];
#pragma unroll
    for (int tt = 0; tt < 9; ++tt) {
        float bb = (tt < NT) ? b1p[(TLO + tt) * 16 + n] : 0.f;
        acc2own[tt] = (f32x4){bb, bb, bb, bb};
    }
    f32x4 zacc;
    {
        int pc = wv * 16 + n;               // packed z col; orig r = (pc>>1)+64*(pc&1)
        float bz = b2[(pc >> 1) + 64 * (pc & 1)];
        zacc = (f32x4){bz, bz, bz, bz};
    }

    // rank-1 coefficients: W0[unit(off1(i)+j)][i], bf16-rounded (matches W0f's rounding)
    float w0d[8], w0d16[8];
#pragma unroll
    for (int k = 0; k < 8; ++k) {
        const int i = 8 * wv + k;
        float v = 0.f, v16 = 0.f;
        if (i < 63) {
            v = bfrnd(W0[unitOf(off1(i) + n) * 64 + i]);
            if (i < 16) v16 = bfrnd(W0[unitOf(off1(i) + 16) * 64 + i]);
        }
        w0d[k] = v; w0d16[k] = v16;
    }

    f32x4 ldjacc = {0.f, 0.f, 0.f, 0.f};
    bf16x8 w1A[9], w1B[9], w2E, w2O, w0fa, w0fb, w0fc;

    BAR();
    if (t < 16) xhist[t][0] = (short)0x3F80;   // bias col = 1.0 (wave 0, same-wave first use)
    float ureg[4];
#pragma unroll
    for (int r = 0; r < 4; ++r) ureg[r] = uT[8 * wv + (n >> 1)][aq * 4 + r];

    // ---- window-boundary catch-up: batch-apply previous window's groups ----
    auto catchup = [&](int w) {
        // zacc: groups 8w-9 .. 8w-2
#pragma unroll
        for (int gk = 0; gk < 8; ++gk) {
            const int g = 8 * w - 9 + gk;
            if (g >= 0) {
                bf16x8 a3 = *(const bf16x8*)&h2w[(g >> 3) & 1][g & 7][n][aq * 8];
                bf16x8 wb = *(const bf16x8*)&W2f[(((long)g * 8 + wv) * 64 + lane) * 8];
                zacc = MFMA16(a3, wb, zacc);
            }
        }
        // acc2: h1 groups 8(w-1) .. 8w-1 (all < our groups, so apply to ALL own tiles)
        const int pH = (w - 1) & 1;
        const long g0 = 8 * (w - 1);
#pragma unroll
        for (int tt = 0; tt < 9; ++tt)
            if (tt < NT) w1A[tt] = *(const bf16x8*)&W1f[(((g0 + 0) * 64 + TLO + tt) * 64 + lane) * 8];
#pragma unroll 1
        for (int gk = 0; gk < 8; gk += 2) {
#pragma unroll
            for (int tt = 0; tt < 9; ++tt)
                if (tt < NT) w1B[tt] = *(const bf16x8*)&W1f[(((g0 + gk + 1) * 64 + TLO + tt) * 64 + lane) * 8];
            {
                bf16x8 af = *(const bf16x8*)&h1w[pH][gk][n][aq * 8];
#pragma unroll
                for (int tt = 0; tt < 9; ++tt)
                    if (tt < NT) acc2own[tt] = MFMA16(af, w1A[tt], acc2own[tt]);
            }
            if (gk + 2 < 8) {
#pragma unroll
                for (int tt = 0; tt < 9; ++tt)
                    if (tt < NT) w1A[tt] = *(const bf16x8*)&W1f[(((g0 + gk + 2) * 64 + TLO + tt) * 64 + lane) * 8];
            }
            {
                bf16x8 af = *(const bf16x8*)&h1w[pH][gk + 1][n][aq * 8];
#pragma unroll
                for (int tt = 0; tt < 9; ++tt)
                    if (tt < NT) acc2own[tt] = MFMA16(af, w1B[tt], acc2own[tt]);
            }
        }
    };

    // ---- one in-window step (k compile-time via full unroll) ----
    auto step = [&](int wq, int k, bf16x8 (&wApply)[9], bf16x8 (&wLoad)[9], bf16x8& w2S) {
        const int i = 8 * wq + k, g = i - 1;
        // apply h1[g] to own tiles >= tf0(g)  (k==0 is covered by catch-up)
        if (k > 0) {
            const int t0g = (off1(g) >> 4) - TLO;
            bf16x8 af = *(const bf16x8*)&h1w[(g >> 3) & 1][g & 7][n][aq * 8];
#pragma unroll
            for (int tt = 0; tt < 9; ++tt)
                if (tt < NT && tt >= t0g) acc2own[tt] = MFMA16(af, wApply[tt], acc2own[tt]);
        }
        // prefetch W1f group i (consumed next step's apply)
        if (k < 7) {
            const long gl = i;
#pragma unroll
            for (int tt = 0; tt < 9; ++tt)
                if (tt < NT) wLoad[tt] = *(const bf16x8*)&W1f[((gl * 64 + TLO + tt) * 64 + lane) * 8];
        }
        // finalize h2[g] from own accumulator (guarded static indexing, wave-uniform tf0)
        if (g >= 0) {
            const int og = off1(g), cg = cntg(g);
            const int tf0 = (og >> 4) - TLO, tfl = ((og + cg - 1) >> 4) - TLO;
            const int p2 = (g >> 3) & 1, s2 = g & 7;
            const int j0 = (tf0 + TLO) * 16 + n - og;
            const int j1 = (tfl + TLO) * 16 + n - og;
#pragma unroll
            for (int tt = 0; tt < 9; ++tt) {
                if (tt == tf0 && j0 >= 0 && j0 < cg) {
#pragma unroll
                    for (int r = 0; r < 4; ++r) {
                        float v = acc2own[tt][r];
                        h2w[p2][s2][aq * 4 + r][j0] = f2bf(v > 0.f ? v : 0.f);
                    }
                }
                if (tfl != tf0 && tt == tfl && j1 < cg) {
#pragma unroll
                    for (int r = 0; r < 4; ++r) {
                        float v = acc2own[tt][r];
                        h2w[p2][s2][aq * 4 + r][j1] = f2bf(v > 0.f ? v : 0.f);
                    }
                }
            }
            if (cg == 16 && n == 0) {   // keep col16 zero on 16-wide slot reuse
#pragma unroll
                for (int r = 0; r < 4; ++r) h2w[p2][s2][aq * 4 + r][16] = 0;
            }
        }
        // partial h1[i] MFMAs over xhist cols 0..i (col i+1 still zero here)
        f32x4 d0p = {0.f, 0.f, 0.f, 0.f}, d1p = {0.f, 0.f, 0.f, 0.f};
        const bool doH1 = (i < 63);
        if (doH1) {
            bf16x8 ax0 = *(const bf16x8*)&xhist[n][aq * 8];
            d0p = MFMA16(ax0, w0fa, d0p);
            if (i >= 32) {
                bf16x8 ax1 = *(const bf16x8*)&xhist[n][32 + aq * 8];
                d0p = MFMA16(ax1, w0fb, d0p);
            }
            if (i < 16) d1p = MFMA16(ax0, w0fc, d1p);
        }
        // zacc += h2[g] * W2 (same-wave LDS round trip)
        if (g >= 0) {
            bf16x8 af3 = *(const bf16x8*)&h2w[(g >> 3) & 1][g & 7][n][aq * 8];
            zacc = MFMA16(af3, w2S, zacc);
        }
        if (k < 7) {
            const long gp = (i + 1 < 63) ? i + 1 : 62;
            w2S = *(const bf16x8*)&W2f[((gp * 8 + wv) * 64 + lane) * 8];
        }
        // extract x_i (packed cols 2i = mu, 2i+1 = sigma live in lanes n0, n0+1)
        const int n0 = 2 * k;
        f32x4 sgv;
#pragma unroll
        for (int r = 0; r < 4; ++r) sgv[r] = __shfl_xor(zacc[r], 1);
        float xv[4];
        if (n == n0) {
#pragma unroll
            for (int r = 0; r < 4; ++r) {
                const float sg = sgv[r], mu = zacc[r];
                const float x = ureg[r] * __expf(sg) + mu;
                ldjacc[r] += sg;
                xv[r] = x;
                xLs[aq * 4 + r][i] = x;
                if (doH1) xhist[aq * 4 + r][i + 1] = f2bf(x);
            }
        }
        // rank-1 finish + publish h1[i]
        if (doH1) {
            const int pi = (i >> 3) & 1, si = i & 7;
#pragma unroll
            for (int r = 0; r < 4; ++r) {
                float xb = bfrnd(__shfl(xv[r], (lane & 48) | n0));
                float h = d0p[r] + xb * w0d[k];
                h1w[pi][si][aq * 4 + r][n] = f2bf(h > 0.f ? h : 0.f);
                if (n == 0) {
                    float h16 = (i < 16) ? (d1p[r] + xb * w0d16[k]) : 0.f;
                    h1w[pi][si][aq * 4 + r][16] = f2bf(h16 > 0.f ? h16 : 0.f);
                }
            }
            if (k < 7) {   // prefetch W0f frags for group i+1
                const long gb = i + 1;
                w0fa = *(const bf16x8*)&W0f[((gb * 4 + 0) * 64 + lane) * 8];
                w0fb = *(const bf16x8*)&W0f[((gb * 4 + 1) * 64 + lane) * 8];
                w0fc = *(const bf16x8*)&W0f[((gb * 4 + 2) * 64 + lane) * 8];
            }
        }
    };

    // ---- 8 windows, ONE barrier each ----
#pragma unroll 1
    for (int w = 0; w < 8; ++w) {
        if (wv == w) {
            __builtin_amdgcn_s_setprio(1);
            const long i0 = 8 * w;
            if (w > 0) w2E = *(const bf16x8*)&W2f[(((i0 - 1) * 8 + wv) * 64 + lane) * 8];
            w2O = *(const bf16x8*)&W2f[((i0 * 8 + wv) * 64 + lane) * 8];
            w0fa = *(const bf16x8*)&W0f[((i0 * 4 + 0) * 64 + lane) * 8];
            w0fb = *(const bf16x8*)&W0f[((i0 * 4 + 1) * 64 + lane) * 8];
            w0fc = *(const bf16x8*)&W0f[((i0 * 4 + 2) * 64 + lane) * 8];
            if (w > 0) catchup(w);
#pragma unroll
            for (int k = 0; k < 8; k += 2) {
                step(w, k,     w1B, w1A, w2E);
                step(w, k + 1, w1A, w1B, w2O);
            }
#pragma unroll
            for (int r = 0; r < 4; ++r) {   // ldj partial for this wave's 8 steps
                float v = ldjacc[r];
                v += __shfl_xor(v, 2);
                v += __shfl_xor(v, 4);
                v += __shfl_xor(v, 8);
                if (n == 0) ldjpart[wv][aq * 4 + r] = v;
            }
            __builtin_amdgcn_s_setprio(0);
        } else if (w > 0 && wv > w) {
            catchup(w);
        }
        BAR();
    }

    if (t < 256) {
        int r = t >> 4, c = (t & 15) * 4;
        float4 v;
        v.x = xLs[r][c]; v.y = xLs[r][c + 1]; v.z = xLs[r][c + 2]; v.w = xLs[r][c + 3];
        *(float4*)&out[(long)(rowbase + r) * 64 + c] = v;
    }
    if (t < 16) {
        float s = 0.f;
#pragma unroll
        for (int w2 = 0; w2 < 8; ++w2) s += ldjpart[w2][t];
        out[(long)BATCH * 64 + rowbase + t] = s;
    }
}

extern "C" void kernel_launch(void* const* d_in, const int* in_sizes, int n_in,
                              void* d_out, int out_size, void* d_ws, size_t ws_size,
                              hipStream_t stream) {
    (void)in_sizes; (void)n_in; (void)out_size; (void)ws_size;
    const float* u  = (const float*)d_in[0];
    const float* W0 = (const float*)d_in[1];
    const float* b0 = (const float*)d_in[2];
    const float* W1 = (const float*)d_in[3];
    const float* b1 = (const float*)d_in[4];
    const float* W2 = (const float*)d_in[5];
    const float* b2 = (const float*)d_in[6];
    float* out = (float*)d_out;

    // d_ws layout (bytes): W1f 4,128,768 | W2f 516,096 | W0f 258,048 | b1p 4,096
    short* W1f = (short*)d_ws;
    short* W2f = (short*)((char*)d_ws + 4128768);
    short* W0f = (short*)((char*)d_ws + 4128768 + 516096);
    float* b1p = (float*)((char*)d_ws + 4128768 + 516096 + 258048);

    prep6<<<dim3(89), dim3(512), 0, stream>>>(W0, b0, W1, b1, W2, W1f, W2f, W0f, b1p);
    made7<<<dim3(BATCH / 16), dim3(NTHR), 0, stream>>>(u, b2, W0, W1f, W2f, W0f, b1p, out);
}